// Round 1
// baseline (650.500 us; speedup 1.0000x reference)
//
#include <hip/hip_runtime.h>
#include <stdint.h>

// C = x @ W, W block-sparse 32x32, layout (i+j)%4==0 on 128x128 block grid.
// Decomposes into 4 dense GEMMs (group g = j%4): M=16384, N=1024, K=1024.
// weight block for (i,j): k = i*32 + (j>>2)   (row-major nonzero order)
//
// Pass 1 (wprep): weight[4096][32][32] f32 -> Bp[4][1024][1024] bf16 in d_ws:
//   Bp[g][s*32+c][t*32+r] = weight[(g0+4t)*32+s][r][c],  g0=(4-g)&3
// Pass 2 (bsmm): per-group GEMM, 128x128 tile, 4 waves, BK=64,
//   double-buffered LDS, XOR-swizzled (row&7)<<4, reg-staged A w/ fp32->bf16.

#define TOK  16384
#define INF  4096
#define OUTF 4096

typedef float f32x4 __attribute__((ext_vector_type(4)));
typedef short s16x8 __attribute__((ext_vector_type(8)));

__device__ __forceinline__ uint32_t pack2bf(float lo, float hi) {
  // round-half-up bf16 conversion, packed pair (lo in low 16 bits)
  uint32_t a = __builtin_bit_cast(uint32_t, lo);
  uint32_t b = __builtin_bit_cast(uint32_t, hi);
  return ((a + 0x8000u) >> 16) | ((b + 0x8000u) & 0xFFFF0000u);
}

// ---------------- pass 1: weight convert + per-block transpose ----------------
__global__ __launch_bounds__(256) void wprep(const float* __restrict__ W,
                                             ushort* __restrict__ Bp) {
  const int k = blockIdx.x;              // 0..4095, one weight block
  const int i = k >> 5, s = k & 31;
  const int g0 = i & 3;
  const int g = (4 - g0) & 3;            // group = j%4 for this block
  const int t = i >> 2;                  // K-block index within group
  __shared__ float lt[32][33];
  const int tid = threadIdx.x;
  const int r = tid >> 3, c0 = (tid & 7) << 2;
  float4 v = *(const float4*)(W + ((size_t)k << 10) + r * 32 + c0);
  lt[c0 + 0][r] = v.x;
  lt[c0 + 1][r] = v.y;
  lt[c0 + 2][r] = v.z;
  lt[c0 + 3][r] = v.w;
  __syncthreads();
  const int c = tid >> 3, r0 = (tid & 7) << 2;
  ushort4 o;
  o.x = (ushort)((__builtin_bit_cast(uint32_t, lt[c][r0 + 0]) + 0x8000u) >> 16);
  o.y = (ushort)((__builtin_bit_cast(uint32_t, lt[c][r0 + 1]) + 0x8000u) >> 16);
  o.z = (ushort)((__builtin_bit_cast(uint32_t, lt[c][r0 + 2]) + 0x8000u) >> 16);
  o.w = (ushort)((__builtin_bit_cast(uint32_t, lt[c][r0 + 3]) + 0x8000u) >> 16);
  *(ushort4*)(Bp + ((size_t)g << 20) + (size_t)(s * 32 + c) * 1024 + t * 32 + r0) = o;
}

// ---------------- pass 2: grouped GEMM ----------------
// grid 4096 = 4 groups x 128 mt x 8 nt. XCD-chunked swizzle: XCD c gets one
// contiguous 512-tile chunk (one group-half): 4 MB x-panel stays L2-resident.
__global__ __launch_bounds__(256, 2) void bsmm(const float* __restrict__ X,
                                               const ushort* __restrict__ Bp,
                                               float* __restrict__ O) {
  __shared__ uint4 lds4[4096];           // 64 KiB: buf{0,1} x {A 16K, B 16K}
  char* lds = (char*)lds4;

  const int bid = blockIdx.x;
  const int swz = ((bid & 7) << 9) | (bid >> 3);   // bijective, 4096%8==0
  const int g  = swz >> 10;
  const int rr = swz & 1023;
  const int mt = rr >> 3, nt = rr & 7;             // nt fast: 8 tiles share x rows
  const int g0 = (4 - g) & 3;
  const int m0 = mt << 7;
  const int n0 = nt << 7;
  const int tid = threadIdx.x;

  // ---- A staging: 128 rows x 64 cols fp32 -> bf16 LDS [row][kk], 128B rows
  // thread -> 8 float4; feature f(kk) = g0*32 + q*256 + h*128 + (kk&31)
  const int arow = tid >> 4;             // 0..15
  const int ac4  = tid & 15;
  const int ah   = ac4 >> 3;             // which 32-block half (h)
  const int acj  = ac4 & 7;
  const float* xp = X + (size_t)(m0 + arow) * INF + g0 * 32 + ah * 128 + (acj << 2);
  const uint32_t awoff = (uint32_t)((ah * 64 + acj * 8) ^ ((arow & 7) << 4));

  // ---- B staging: 128 rows(n) x 64 cols(kk) bf16 from Bp panel, 4x uint4
  const int bro = tid >> 3;              // 0..31
  const int bh  = tid & 7;
  const ushort* bp = Bp + ((size_t)g << 20) + (size_t)(n0 + bro) * 1024 + (bh << 3);
  const uint32_t bwoff = (uint32_t)(16384 + ((bh << 4) ^ ((bro & 7) << 4)));

  // ---- fragment read constants (wave grid 2x2, 64x64 per wave, 4x4 frags)
  const int lane = tid & 63, wid = tid >> 6;
  const int wr = wid >> 1, wc = wid & 1;
  const int lr = lane & 15, lg = lane >> 4;
  const int koff0 = ((lg << 4) + 0)  ^ ((lr & 7) << 4);
  const int koff1 = ((lg << 4) + 64) ^ ((lr & 7) << 4);
  const int arb = (wr * 64 + lr) * 128;            // + mi*2048
  const int brb = 16384 + (wc * 64 + lr) * 128;    // + ni*2048

  float4 areg[8];
  uint4  breg[4];

  auto issueA = [&](int q) {
#pragma unroll
    for (int l = 0; l < 8; ++l)
      areg[l] = *(const float4*)(xp + (q << 8) + (size_t)l * (16 * INF));
  };
  auto issueB = [&](int q) {
#pragma unroll
    for (int it = 0; it < 4; ++it)
      breg[it] = *(const uint4*)(bp + (q << 6) + it * (32 * 1024));
  };
  auto stageA = [&](int buf) {
    char* base = lds + (buf << 15);
#pragma unroll
    for (int l = 0; l < 8; ++l) {
      uint2 d;
      d.x = pack2bf(areg[l].x, areg[l].y);
      d.y = pack2bf(areg[l].z, areg[l].w);
      *(uint2*)(base + ((l * 16 + arow) * 128 + awoff)) = d;
    }
  };
  auto stageB = [&](int buf) {
    char* base = lds + (buf << 15);
#pragma unroll
    for (int it = 0; it < 4; ++it)
      *(uint4*)(base + ((it * 32 + bro) * 128 + bwoff)) = breg[it];
  };

  // prologue: stage q=0 into buf0, have q=1 loads in flight
  issueA(0); issueB(0);
  stageA(0); stageB(0);
  issueA(1); issueB(1);
  __syncthreads();

  f32x4 acc[4][4];
#pragma unroll
  for (int mi = 0; mi < 4; ++mi)
#pragma unroll
    for (int ni = 0; ni < 4; ++ni)
      acc[mi][ni] = f32x4{0.f, 0.f, 0.f, 0.f};

#pragma unroll 2
  for (int q = 0; q < 16; ++q) {
    const int cur = q & 1;
    char* base = lds + (cur << 15);
    s16x8 af0[4], af1[4], bf0[4], bf1[4];
#pragma unroll
    for (int mi = 0; mi < 4; ++mi) {
      af0[mi] = *(const s16x8*)(base + arb + mi * 2048 + koff0);
      af1[mi] = *(const s16x8*)(base + arb + mi * 2048 + koff1);
    }
#pragma unroll
    for (int ni = 0; ni < 4; ++ni) {
      bf0[ni] = *(const s16x8*)(base + brb + ni * 2048 + koff0);
      bf1[ni] = *(const s16x8*)(base + brb + ni * 2048 + koff1);
    }
    // T14 split: write next tile (loads issued last iter), then issue q+2
    if (q < 15) { stageA(cur ^ 1); stageB(cur ^ 1); }
    if (q < 14) { issueA(q + 2); issueB(q + 2); }
#pragma unroll
    for (int mi = 0; mi < 4; ++mi)
#pragma unroll
      for (int ni = 0; ni < 4; ++ni)
        acc[mi][ni] = __builtin_amdgcn_mfma_f32_16x16x32_bf16(af0[mi], bf0[ni], acc[mi][ni], 0, 0, 0);
#pragma unroll
    for (int mi = 0; mi < 4; ++mi)
#pragma unroll
      for (int ni = 0; ni < 4; ++ni)
        acc[mi][ni] = __builtin_amdgcn_mfma_f32_16x16x32_bf16(af1[mi], bf1[ni], acc[mi][ni], 0, 0, 0);
    __syncthreads();
  }

  // epilogue: C/D layout col=lane&15, row=(lane>>4)*4+reg (verified m89/m91)
  // group col n -> global col = g*32 + (n>>5)*128 + (n&31)
#pragma unroll
  for (int mi = 0; mi < 4; ++mi) {
    const int rowg = m0 + wr * 64 + mi * 16 + lg * 4;
#pragma unroll
    for (int ni = 0; ni < 4; ++ni) {
      const int nn = n0 + wc * 64 + ni * 16 + lr;
      const int gcol = g * 32 + ((nn >> 5) << 7) + (nn & 31);
      float* op = O + (size_t)rowg * OUTF + gcol;
#pragma unroll
      for (int r = 0; r < 4; ++r)
        op[(size_t)r * OUTF] = acc[mi][ni][r];
    }
  }
}

extern "C" void kernel_launch(void* const* d_in, const int* in_sizes, int n_in,
                              void* d_out, int out_size, void* d_ws, size_t ws_size,
                              hipStream_t stream) {
  const float* x = (const float*)d_in[0];
  const float* w = (const float*)d_in[1];
  // d_in[2]=ri, d_in[3]=ci unused: layout is analytic (k = i*32 + (j>>2))
  ushort* Bp = (ushort*)d_ws;            // needs 8,388,608 bytes
  float* out = (float*)d_out;
  hipLaunchKernelGGL(wprep, dim3(4096), dim3(256), 0, stream, w, Bp);
  hipLaunchKernelGGL(bsmm, dim3(4096), dim3(256), 0, stream, x, Bp, out);
}